// Round 6
// baseline (339.614 us; speedup 1.0000x reference)
//
#include <hip/hip_runtime.h>
#include <hip/hip_bf16.h>

// Grouped GEMM (MoE): out[t,o] = sum_k x[t,k]*W[e,o,k] + bias[e,o]
// E=64, 4096 tok/expert, D_IN=D_OUT=512, f32 in/out. bf16 MFMA.
// Key insight: with wave-grid 1M x 4N, B-fragments are WAVE-PRIVATE -> load them
// direct global->reg (no LDS round trip). W pre-converted to bf16 in d_ws.
// A (shared by all 4 waves) goes through 16KB double-buffered LDS with the
// proven XOR swizzle, reg-staged dist-2. 1 barrier + 1 lgkm drain per K-step,
// no vmcnt(0) in-loop (counted waits via register deps). XCD block swizzle.

#define NEXPERT 64
#define DIN 512
#define DOUT 512
#define TPE 4096
#define BM 128
#define BN 256
#define BK 32
#define NKT (DIN / BK)  // 16

typedef __attribute__((ext_vector_type(8))) __bf16 bf16x8;
typedef __attribute__((ext_vector_type(4))) __bf16 bf16x4;
typedef __attribute__((ext_vector_type(4))) float f32x4;

__global__ __launch_bounds__(256)
void convert_w_kernel(const float* __restrict__ w, __bf16* __restrict__ wb) {
  size_t i = ((size_t)blockIdx.x * 256 + threadIdx.x) * 8;
  f32x4 a = *(const f32x4*)(w + i);
  f32x4 b = *(const f32x4*)(w + i + 4);
  bf16x8 r;
  r[0] = (__bf16)a[0]; r[1] = (__bf16)a[1]; r[2] = (__bf16)a[2]; r[3] = (__bf16)a[3];
  r[4] = (__bf16)b[0]; r[5] = (__bf16)b[1]; r[6] = (__bf16)b[2]; r[7] = (__bf16)b[3];
  *(bf16x8*)(wb + i) = r;
}

template <bool WB16>
__global__ __launch_bounds__(256, 2)
void moe_gemm(const float* __restrict__ x, const void* __restrict__ wsrc,
              const float* __restrict__ bias, float* __restrict__ out) {
  // A only: [2 buffers][128 rows][64B rows of 32 bf16], XOR-swizzled chunks.
  __shared__ __align__(16) unsigned char sA[2][BM * BK * 2];  // 8KB each

  // XCD swizzle: 4096 blocks = 8 XCDs x 512 contiguous.
  int bid = blockIdx.x;
  int swzb = (bid & 7) * 512 + (bid >> 3);
  int e  = swzb >> 6;   // 64 blocks per expert
  int rr = swzb & 63;
  int mt = rr >> 1;     // A-panel shared by 2 consecutive blocks (nt inner)
  int nt = rr & 1;

  const int tid  = threadIdx.x;
  const int lane = tid & 63;
  const int wn   = tid >> 6;    // wave 0..3 -> N slice of 64
  const int r15  = lane & 15;
  const int kg   = lane >> 4;

  // ---- A staging ownership: c4 = f32x4 col (0..7), tr = row base (0..31) ----
  const int c4 = tid & 7;
  const int tr = tid >> 3;
  const float* aG = x + ((size_t)e * TPE + (size_t)mt * BM + tr) * DIN + c4 * 4;
  const int wrBase = tr * 64 + (((c4 >> 1) ^ ((tr >> 1) & 3)) << 4) + (c4 & 1) * 8;

  // ---- A frag read base (chunk kg, swizzled by (r15>>1)&3) ----
  const int chz = (kg ^ ((r15 >> 1) & 3)) << 4;
  const int aRd = r15 * 64 + chz;  // + mi*1024

  // ---- B frag source: per-lane direct global (row = out-col, 8 k-contig) ----
  const size_t bRow = (size_t)(e * DOUT + nt * BN + wn * 64 + r15) * DIN + kg * 8;
  const __bf16* bPb = (const __bf16*)wsrc + bRow;
  const float*  bPf = (const float*)wsrc + bRow;

  f32x4 sa0[4], sa1[4];      // A staging sets (dist-2)
  bf16x8 b0v[4], b1v[4];     // B frag sets (dist-1)

#define ISSUEA(kt, Sr)                                                      \
  { _Pragma("unroll") for (int i = 0; i < 4; ++i)                           \
      Sr[i] = *(const f32x4*)(aG + (size_t)i * 32 * DIN + (kt) * BK); }

#define WRITEA(dbuf, Sr)                                                    \
  { _Pragma("unroll") for (int i = 0; i < 4; ++i) {                         \
      bf16x4 c;                                                             \
      c[0] = (__bf16)Sr[i][0]; c[1] = (__bf16)Sr[i][1];                     \
      c[2] = (__bf16)Sr[i][2]; c[3] = (__bf16)Sr[i][3];                     \
      *(bf16x4*)(&sA[dbuf][wrBase + i * 2048]) = c; } }

#define LOADB(kt, Br)                                                       \
  { if constexpr (WB16) {                                                   \
      _Pragma("unroll") for (int n = 0; n < 4; ++n)                         \
        Br[n] = *(const bf16x8*)(bPb + (size_t)n * 16 * DIN + (kt) * BK);   \
    } else {                                                                \
      _Pragma("unroll") for (int n = 0; n < 4; ++n) {                       \
        f32x4 lo = *(const f32x4*)(bPf + (size_t)n * 16 * DIN + (kt) * BK); \
        f32x4 hi = *(const f32x4*)(bPf + (size_t)n * 16 * DIN + (kt) * BK + 4); \
        bf16x8 rv;                                                          \
        rv[0]=(__bf16)lo[0]; rv[1]=(__bf16)lo[1]; rv[2]=(__bf16)lo[2]; rv[3]=(__bf16)lo[3]; \
        rv[4]=(__bf16)hi[0]; rv[5]=(__bf16)hi[1]; rv[6]=(__bf16)hi[2]; rv[7]=(__bf16)hi[3]; \
        Br[n] = rv; } } }

#define MFMAS(Bv)                                                           \
  { _Pragma("unroll") for (int mi = 0; mi < 8; ++mi)                        \
      _Pragma("unroll") for (int ni = 0; ni < 4; ++ni)                      \
        acc[mi][ni] = __builtin_amdgcn_mfma_f32_16x16x32_bf16(              \
            af[mi], Bv[ni], acc[mi][ni], 0, 0, 0); }

  f32x4 acc[8][4];
#pragma unroll
  for (int m = 0; m < 8; ++m)
#pragma unroll
    for (int n = 0; n < 4; ++n) acc[m][n] = (f32x4)0.f;

  // Prologue: A(0)->LDS buf0 (one-time vmcnt stall), A(1)+B(0) in flight.
  ISSUEA(0, sa0);
  ISSUEA(1, sa1);
  LOADB(0, b0v);
  WRITEA(0, sa0);
  asm volatile("s_waitcnt lgkmcnt(0)" ::: "memory");
  __builtin_amdgcn_s_barrier();

#pragma unroll
  for (int t = 0; t < NKT; ++t) {
    const int d = t & 1;
    bf16x8 af[8];
#pragma unroll
    for (int mi = 0; mi < 8; ++mi)
      af[mi] = *(const bf16x8*)(&sA[d][aRd + mi * 1024]);

    if (d == 0) {
      if (t + 1 < NKT) LOADB(t + 1, b1v);          // B dist-1 prefetch
      if (t + 2 < NKT) ISSUEA(t + 2, sa0);         // A dist-2 issue
      if (t + 1 < NKT) WRITEA(1, sa1);             // A write (issued 1 step ago)
      __builtin_amdgcn_s_setprio(1);
      MFMAS(b0v);
      __builtin_amdgcn_s_setprio(0);
    } else {
      if (t + 1 < NKT) LOADB(t + 1, b0v);
      if (t + 2 < NKT) ISSUEA(t + 2, sa1);
      if (t + 1 < NKT) WRITEA(0, sa0);
      __builtin_amdgcn_s_setprio(1);
      MFMAS(b1v);
      __builtin_amdgcn_s_setprio(0);
    }

    if (t + 1 < NKT) {
      asm volatile("s_waitcnt lgkmcnt(0)" ::: "memory");  // publish A writes
      __builtin_amdgcn_s_barrier();
    }
  }

  // Epilogue: C/D layout col = lane&15, row = (lane>>4)*4 + j  [m89/m91]
  float bv[4];
  const float* bp = bias + (size_t)e * DOUT + nt * BN + wn * 64 + r15;
#pragma unroll
  for (int n = 0; n < 4; ++n) bv[n] = bp[n * 16];

  const int q4 = (lane >> 4) * 4;
  float* Cb = out + ((size_t)e * TPE + (size_t)mt * BM) * DOUT + nt * BN + wn * 64;
#pragma unroll
  for (int m = 0; m < 8; ++m) {
#pragma unroll
    for (int j = 0; j < 4; ++j) {
      float* pr = Cb + (size_t)(m * 16 + q4 + j) * DOUT;
#pragma unroll
      for (int n = 0; n < 4; ++n)
        pr[n * 16 + r15] = acc[m][n][j] + bv[n];
    }
  }
#undef ISSUEA
#undef WRITEA
#undef LOADB
#undef MFMAS
}

extern "C" void kernel_launch(void* const* d_in, const int* in_sizes, int n_in,
                              void* d_out, int out_size, void* d_ws, size_t ws_size,
                              hipStream_t stream) {
  const float* x    = (const float*)d_in[0];
  // d_in[1] = num_experts_per_token (int64): balanced, unused
  const float* w    = (const float*)d_in[2];
  const float* bias = (const float*)d_in[3];
  float* out        = (float*)d_out;

  const size_t wElems = (size_t)NEXPERT * DOUT * DIN;        // 16.78M
  const size_t needWs = wElems * sizeof(__hip_bfloat16);     // 33.5MB
  dim3 grid(NEXPERT * (TPE / BM) * (DOUT / BN));             // 4096
  dim3 block(256);

  if (ws_size >= needWs) {
    dim3 cgrid(wElems / 8 / 256);                            // 8192
    hipLaunchKernelGGL(convert_w_kernel, cgrid, block, 0, stream,
                       w, (__bf16*)d_ws);
    hipLaunchKernelGGL(moe_gemm<true>, grid, block, 0, stream,
                       x, (const void*)d_ws, bias, out);
  } else {
    hipLaunchKernelGGL(moe_gemm<false>, grid, block, 0, stream,
                       x, (const void*)w, bias, out);
  }
}

// Round 7
// 288.590 us; speedup vs baseline: 1.1768x; 1.1768x over previous
//
#include <hip/hip_runtime.h>
#include <hip/hip_bf16.h>

// Grouped GEMM (MoE): out[t,o] = sum_k x[t,k]*W[e,o,k] + bias[e,o]
// E=64, 4096 tok/expert, D_IN=D_OUT=512, f32 in/out. bf16 MFMA.
// R7: counted-vmcnt pipeline. W pre-packed (bf16, gload_lds tile order with
// inverse-XOR swizzle baked into storage) -> B staged via global_load_lds DMA.
// A reg-staged f32->bf16 into XOR-swizzled LDS (dist-2 issue / dist-1 write).
// One barrier + one counted vmcnt per K-step; vmcnt(0) never in-loop.
// Tile 128x256, 4 waves (1M x 4N), per-wave 128x64, BK=32, NKT=16 unrolled.

#define NEXPERT 64
#define DIN 512
#define DOUT 512
#define TPE 4096
#define BM 128
#define BN 256
#define BK 32
#define NKT 16

typedef __attribute__((ext_vector_type(8))) __bf16 bf16x8;
typedef __attribute__((ext_vector_type(4))) __bf16 bf16x4;
typedef __attribute__((ext_vector_type(4))) float f32x4;

// ---------------- W pack kernel: f32 W -> bf16 d_ws in gload_lds order ------
// Slot S = (((e*2+nt)*16 + kt)*16 + c)*64 + l  holds 8 bf16:
//   row o = nt*256 + c*16 + (l>>2),  k = kt*32 + kg(l)*8..,  kg(l)=(l&3)^((l>>3)&3)
// so that a linear gload_lds fill of chunk c reproduces the LDS layout
//   byte(row,kg) = row*64 + (kg ^ ((row>>1)&3))*16   (the proven XOR swizzle).
__global__ __launch_bounds__(256)
void pack_w_kernel(const float* __restrict__ w, __bf16* __restrict__ wp) {
  int S = blockIdx.x * 256 + threadIdx.x;          // 0 .. 2^21-1
  int l  = S & 63;
  int c  = (S >> 6) & 15;
  int kt = (S >> 10) & 15;
  int nt = (S >> 14) & 1;
  int e  = S >> 15;
  int o  = nt * 256 + c * 16 + (l >> 2);
  int kg = (l & 3) ^ ((l >> 3) & 3);
  const float* src = w + ((size_t)(e * DOUT + o)) * DIN + kt * BK + kg * 8;
  f32x4 lo = *(const f32x4*)(src);
  f32x4 hi = *(const f32x4*)(src + 4);
  bf16x8 r;
  r[0]=(__bf16)lo[0]; r[1]=(__bf16)lo[1]; r[2]=(__bf16)lo[2]; r[3]=(__bf16)lo[3];
  r[4]=(__bf16)hi[0]; r[5]=(__bf16)hi[1]; r[6]=(__bf16)hi[2]; r[7]=(__bf16)hi[3];
  *(bf16x8*)(wp + (size_t)S * 8) = r;
}

// ---------------- main kernel ----------------------------------------------
__global__ __launch_bounds__(256, 2)
void moe_gemm8(const float* __restrict__ x, const __bf16* __restrict__ wp,
               const float* __restrict__ bias, float* __restrict__ out) {
  __shared__ __align__(16) unsigned char sA[2][BM * BK * 2];  // 8KB each
  __shared__ __align__(16) unsigned char sB[2][BN * BK * 2];  // 16KB each

  // XCD swizzle: 4096 blocks = 8 XCDs x 512 contiguous.
  int bid = blockIdx.x;
  int swzb = (bid & 7) * 512 + (bid >> 3);
  int e  = swzb >> 6;
  int rr = swzb & 63;
  int mt = rr >> 1;      // A-panel shared by 2 consecutive blocks (nt inner)
  int nt = rr & 1;

  const int tid  = threadIdx.x;
  const int lane = tid & 63;
  const int wn   = tid >> 6;     // wave 0..3 -> N slice of 64
  const int r15  = lane & 15;
  const int kg   = lane >> 4;

  // A staging: c4 = f32x4 col, tr = row base; proven XOR-swizzled write.
  const int c4 = tid & 7;
  const int tr = tid >> 3;
  const float* aG = x + ((size_t)e * TPE + (size_t)mt * BM + tr) * DIN + c4 * 4;
  const int wrBase = tr * 64 + (((c4 >> 1) ^ ((tr >> 1) & 3)) << 4) + (c4 & 1) * 8;

  // frag read bases (chunk kg, swizzled by (r15>>1)&3)
  const int chz = (kg ^ ((r15 >> 1) & 3)) << 4;
  const int aRd = r15 * 64 + chz;                 // + mi*1024
  const int bRd = (wn * 64 + r15) * 64 + chz;     // + ni*1024

  // B DMA source: packed tile (e,nt,kt), chunks wn*4+i, per-lane 16B.
  const __bf16* bSrc =
      wp + ((size_t)(((e * 2 + nt) * 16) * 16 + wn * 4) * 64 + lane) * 8;
  // + kt*8192 per K-step, + i*512 per chunk.

  f32x4 sa0[4], sa1[4];

#define GLOADB(kt, dbuf)                                                     \
  { _Pragma("unroll") for (int i = 0; i < 4; ++i)                            \
      __builtin_amdgcn_global_load_lds(                                      \
          (const __attribute__((address_space(1))) void*)(bSrc +             \
              (size_t)(kt) * 8192 + i * 512),                                \
          (__attribute__((address_space(3))) void*)(&sB[dbuf][(wn * 4 + i) * 1024]), \
          16, 0, 0); }

#define ISSUEA(kt, Sr)                                                       \
  { _Pragma("unroll") for (int i = 0; i < 4; ++i)                            \
      Sr[i] = *(const f32x4*)(aG + (size_t)i * 32 * DIN + (kt) * BK); }

#define WRITEA(dbuf, Sr)                                                     \
  { _Pragma("unroll") for (int i = 0; i < 4; ++i) {                          \
      bf16x4 cc;                                                             \
      cc[0] = (__bf16)Sr[i][0]; cc[1] = (__bf16)Sr[i][1];                    \
      cc[2] = (__bf16)Sr[i][2]; cc[3] = (__bf16)Sr[i][3];                    \
      *(bf16x4*)(&sA[dbuf][wrBase + i * 2048]) = cc; } }

  f32x4 acc[8][4];
#pragma unroll
  for (int m = 0; m < 8; ++m)
#pragma unroll
    for (int n = 0; n < 4; ++n) acc[m][n] = (f32x4)0.f;

  // Prologue. VMEM issue order: B(0), A(0), A(1). WRITEA waits A(0) ->
  // compiler-counted vmcnt(4) (forces B(0)+A(0) done, A(1) stays in flight).
  GLOADB(0, 0);
  ISSUEA(0, sa0);
  ISSUEA(1, sa1);
  WRITEA(0, sa0);
  asm volatile("s_waitcnt lgkmcnt(0)" ::: "memory");
  __builtin_amdgcn_s_barrier();

  // Steady-state invariant at top of step t: outstanding = B(t)[4] + A(t+1)[4];
  // vmcnt(4) waits exactly B(t). (t=0: B(0) already drained, no-op.)
#pragma unroll
  for (int t = 0; t < NKT; ++t) {
    const int d = t & 1;
    if (t == NKT - 1) {
      asm volatile("s_waitcnt vmcnt(0)" ::: "memory");   // only B(15) left
    } else {
      asm volatile("s_waitcnt vmcnt(4)" ::: "memory");
    }
    // P0: next-tile B DMA + frag reads for first MFMA half
    if (t + 1 < NKT) GLOADB(t + 1, d ^ 1);
    bf16x8 bfr[4], af[8];
#pragma unroll
    for (int ni = 0; ni < 4; ++ni)
      bfr[ni] = *(const bf16x8*)(&sB[d][bRd + ni * 1024]);
#pragma unroll
    for (int mi = 0; mi < 4; ++mi)
      af[mi] = *(const bf16x8*)(&sA[d][aRd + mi * 1024]);

    // P1: A-issue dist-2, then MFMA half 1
    if (t + 2 < NKT) {
      if (d == 0) ISSUEA(t + 2, sa0) else ISSUEA(t + 2, sa1)
    }
    __builtin_amdgcn_s_setprio(1);
#pragma unroll
    for (int mi = 0; mi < 4; ++mi)
#pragma unroll
      for (int ni = 0; ni < 4; ++ni)
        acc[mi][ni] = __builtin_amdgcn_mfma_f32_16x16x32_bf16(
            af[mi], bfr[ni], acc[mi][ni], 0, 0, 0);
    __builtin_amdgcn_s_setprio(0);

    // P2: remaining frag reads + A write (dist-1; compiler-counted vmcnt(8))
#pragma unroll
    for (int mi = 4; mi < 8; ++mi)
      af[mi] = *(const bf16x8*)(&sA[d][aRd + mi * 1024]);
    if (t + 1 < NKT) {
      if (d == 0) WRITEA(1, sa1) else WRITEA(0, sa0)
    }

    // P3: MFMA half 2
    __builtin_amdgcn_s_setprio(1);
#pragma unroll
    for (int mi = 4; mi < 8; ++mi)
#pragma unroll
      for (int ni = 0; ni < 4; ++ni)
        acc[mi][ni] = __builtin_amdgcn_mfma_f32_16x16x32_bf16(
            af[mi], bfr[ni], acc[mi][ni], 0, 0, 0);
    __builtin_amdgcn_s_setprio(0);

    if (t + 1 < NKT) {
      asm volatile("s_waitcnt lgkmcnt(0)" ::: "memory");  // publish A writes
      __builtin_amdgcn_s_barrier();
    }
  }

  // Epilogue: C/D layout col = lane&15, row = (lane>>4)*4 + j  [m89/m91]
  float bv[4];
  const float* bp = bias + (size_t)e * DOUT + nt * BN + wn * 64 + r15;
#pragma unroll
  for (int n = 0; n < 4; ++n) bv[n] = bp[n * 16];

  const int q4 = (lane >> 4) * 4;
  float* Cb = out + ((size_t)e * TPE + (size_t)mt * BM) * DOUT + nt * BN + wn * 64;
#pragma unroll
  for (int m = 0; m < 8; ++m) {
#pragma unroll
    for (int j = 0; j < 4; ++j) {
      float* pr = Cb + (size_t)(m * 16 + q4 + j) * DOUT;
#pragma unroll
      for (int n = 0; n < 4; ++n)
        pr[n * 16 + r15] = acc[m][n][j] + bv[n];
    }
  }
#undef GLOADB
#undef ISSUEA
#undef WRITEA
}

// ---------------- fallback (ws too small): R2-proven kernel -----------------
typedef __attribute__((ext_vector_type(8))) __bf16 bf16x8_t;

__device__ __forceinline__ bf16x8 cvt8f(f32x4 lo, f32x4 hi) {
  bf16x8 r;
  r[0]=(__bf16)lo[0]; r[1]=(__bf16)lo[1]; r[2]=(__bf16)lo[2]; r[3]=(__bf16)lo[3];
  r[4]=(__bf16)hi[0]; r[5]=(__bf16)hi[1]; r[6]=(__bf16)hi[2]; r[7]=(__bf16)hi[3];
  return r;
}

__global__ __launch_bounds__(256)
void moe_fallback(const float* __restrict__ x, const float* __restrict__ w,
                  const float* __restrict__ bias, float* __restrict__ out) {
  __shared__ bf16x8 fA[2][512];
  __shared__ bf16x8 fB[2][512];
  int bid = blockIdx.x;
  int swz = (bid & 7) * 1024 + (bid >> 3);
  int e = swz >> 7, rr = swz & 127, mt = rr >> 2, nt = rr & 3;
  const int t = threadIdx.x, lane = t & 63, wave = t >> 6;
  const int wm = wave >> 1, wnn = wave & 1, r15 = lane & 15, kgf = lane >> 4;
  const int rs = r15 * 4 + (kgf ^ ((r15 >> 1) & 3));
  const int row0 = t >> 2, kg0 = t & 3;
  const int slot0 = row0 * 4 + (kg0 ^ ((row0 >> 1) & 3));
  const int slot1 = slot0 + 256;
  const float* Ab = x + ((size_t)e * TPE + (size_t)mt * 128) * DIN;
  const float* Bb = w + ((size_t)e * DOUT + (size_t)nt * 128) * DIN;
  const int offA0 = row0 * DIN + kg0 * 8, offA1 = offA0 + 64 * DIN;
  f32x4 a0l, a0h, a1l, a1h, b0l, b0h, b1l, b1h;
  auto LOAD = [&](int kt) {
    const float* pa0 = Ab + offA0 + kt * 32; const float* pa1 = Ab + offA1 + kt * 32;
    const float* pb0 = Bb + offA0 + kt * 32; const float* pb1 = Bb + offA1 + kt * 32;
    a0l = *(const f32x4*)(pa0); a0h = *(const f32x4*)(pa0 + 4);
    a1l = *(const f32x4*)(pa1); a1h = *(const f32x4*)(pa1 + 4);
    b0l = *(const f32x4*)(pb0); b0h = *(const f32x4*)(pb0 + 4);
    b1l = *(const f32x4*)(pb1); b1h = *(const f32x4*)(pb1 + 4);
  };
  auto STORE = [&](int buf) {
    fA[buf][slot0] = cvt8f(a0l, a0h); fA[buf][slot1] = cvt8f(a1l, a1h);
    fB[buf][slot0] = cvt8f(b0l, b0h); fB[buf][slot1] = cvt8f(b1l, b1h);
  };
  f32x4 acc[4][4];
#pragma unroll
  for (int m = 0; m < 4; ++m)
#pragma unroll
    for (int n = 0; n < 4; ++n) acc[m][n] = (f32x4)0.f;
  LOAD(0); STORE(0); __syncthreads();
  int cur = 0;
  for (int kt = 0; kt < NKT; ++kt) {
    if (kt + 1 < NKT) LOAD(kt + 1);
    bf16x8 af[4], bfr[4];
#pragma unroll
    for (int m = 0; m < 4; ++m) af[m] = fA[cur][wm * 256 + m * 64 + rs];
#pragma unroll
    for (int n = 0; n < 4; ++n) bfr[n] = fB[cur][wnn * 256 + n * 64 + rs];
#pragma unroll
    for (int m = 0; m < 4; ++m)
#pragma unroll
      for (int n = 0; n < 4; ++n)
        acc[m][n] = __builtin_amdgcn_mfma_f32_16x16x32_bf16(af[m], bfr[n], acc[m][n], 0, 0, 0);
    if (kt + 1 < NKT) { STORE(cur ^ 1); __syncthreads(); }
    cur ^= 1;
  }
  float bv[4];
  const float* bp = bias + (size_t)e * DOUT + nt * 128 + wnn * 64 + r15;
#pragma unroll
  for (int n = 0; n < 4; ++n) bv[n] = bp[n * 16];
  const int q4 = (lane >> 4) * 4;
  float* Cb = out + ((size_t)e * TPE + (size_t)mt * 128 + wm * 64) * DOUT + nt * 128 + wnn * 64;
#pragma unroll
  for (int m = 0; m < 4; ++m)
#pragma unroll
    for (int j = 0; j < 4; ++j) {
      float* pr = Cb + (size_t)(m * 16 + q4 + j) * DOUT;
#pragma unroll
      for (int n = 0; n < 4; ++n) pr[n * 16 + r15] = acc[m][n][j] + bv[n];
    }
}

extern "C" void kernel_launch(void* const* d_in, const int* in_sizes, int n_in,
                              void* d_out, int out_size, void* d_ws, size_t ws_size,
                              hipStream_t stream) {
  const float* x    = (const float*)d_in[0];
  // d_in[1] = num_experts_per_token (int64): balanced, unused
  const float* w    = (const float*)d_in[2];
  const float* bias = (const float*)d_in[3];
  float* out        = (float*)d_out;

  const size_t wElems = (size_t)NEXPERT * DOUT * DIN;     // 16.78M
  const size_t needWs = wElems * sizeof(__hip_bfloat16);  // 33.5MB
  dim3 block(256);

  if (ws_size >= needWs) {
    dim3 pgrid(wElems / 8 / 256);                         // 8192
    hipLaunchKernelGGL(pack_w_kernel, pgrid, block, 0, stream, w, (__bf16*)d_ws);
    dim3 grid(NEXPERT * (TPE / BM) * (DOUT / BN));        // 4096
    hipLaunchKernelGGL(moe_gemm8, grid, block, 0, stream,
                       x, (const __bf16*)d_ws, bias, out);
  } else {
    dim3 grid(NEXPERT * 32 * 4);                          // 8192
    hipLaunchKernelGGL(moe_fallback, grid, block, 0, stream, x, w, bias, out);
  }
}